// Round 7
// baseline (233.256 us; speedup 1.0000x reference)
//
#include <hip/hip_runtime.h>
#include <hip/hip_bf16.h>
#include <math.h>

#define N_NODES 100000
#define DIM 128
#define HID 512
#define EDGES 600000
#define SCAN_CHUNK 1024
#define SCAN_NBLK ((N_NODES + SCAN_CHUNK - 1) / SCAN_CHUNK)  // 98
#define MROWS_PAD 100096   // 391 * 256

typedef short bf16x8 __attribute__((ext_vector_type(8)));
typedef float f32x4 __attribute__((ext_vector_type(4)));

// Swizzle convention (rule #21 both-sides): for every bf16 staging buffer
// (X, W1T, W2T, hdn), physical byte offset within a row = logical byte
// offset XOR ((row & 7) << 4). XOR touches bits 4..6 only -> permutes 16-B
// slots within each 128-B chunk; global_load_lds copies 128-B chunks
// verbatim, MFMA-fragment ds_read applies the same XOR -> 2-way (free)
// LDS bank access.

__device__ inline unsigned short f32_to_bf16(float f) {
    unsigned int u = __float_as_uint(f);
    u += 0x7fff + ((u >> 16) & 1);
    return (unsigned short)(u >> 16);
}

// fast GELU: tanh form via hw exp2 + rcp. |gelu_tanh - gelu_erf| <= ~5e-4.
__device__ inline float gelu_f(float x) {
    float x3 = x * x * x;
    float y = 0.7978845608028654f * x + 0.0356774081f * x3;
    float e = exp2f(y * 2.8853900817779268f);                 // exp(2y)
    float t = 1.0f - 2.0f * __builtin_amdgcn_rcpf(e + 1.0f);  // tanh(y)
    return 0.5f * x * (1.0f + t);
}

__device__ inline void gload16(const void* g, void* l) {
    __builtin_amdgcn_global_load_lds(
        (const __attribute__((address_space(1))) unsigned int*)g,
        (__attribute__((address_space(3))) unsigned int*)l,
        16, 0, 0);
}

// ---------------------------------------------------------------------------
// Fused prep kernel: W1 transpose | W2 transpose | h->bf16 convert | dst count
// ---------------------------------------------------------------------------
#define PREP_W1_BLKS 512
#define PREP_W2_BLKS 128
#define PREP_CONV_BLKS 12500                  // N_NODES*32/256
#define PREP_COUNT_BLKS ((EDGES + 255) / 256) // 2344
#define PREP_TOTAL (PREP_W1_BLKS + PREP_W2_BLKS + PREP_CONV_BLKS + PREP_COUNT_BLKS)

__global__ __launch_bounds__(256) void mgl_prep_kernel(
    const float* __restrict__ h, const int* __restrict__ ei,
    const float* __restrict__ W1, const float* __restrict__ W2,
    unsigned short* __restrict__ X, unsigned short* __restrict__ W1T,
    unsigned short* __restrict__ W2T, int* __restrict__ cnt)
{
    int b = blockIdx.x;
    if (b < PREP_W1_BLKS) {
        int n = b;                       // 0..511
        int k = threadIdx.x;             // 0..255
        unsigned short val = f32_to_bf16(W1[(size_t)k * HID + n]);
        int byteoff = (k * 2) ^ ((n & 7) << 4);
        *(unsigned short*)((char*)(W1T + (size_t)n * 256) + byteoff) = val;
        return;
    }
    b -= PREP_W1_BLKS;
    if (b < PREP_W2_BLKS) {
        int n = b;                       // 0..127
        #pragma unroll
        for (int it = 0; it < 2; ++it) {
            int k = threadIdx.x + it * 256;  // 0..511
            unsigned short val = f32_to_bf16(W2[(size_t)k * DIM + n]);
            int byteoff = (k * 2) ^ ((n & 7) << 4);
            *(unsigned short*)((char*)(W2T + (size_t)n * 512) + byteoff) = val;
        }
        return;
    }
    b -= PREP_W2_BLKS;
    if (b < PREP_CONV_BLKS) {
        int t = b * 256 + threadIdx.x;
        if (t >= N_NODES * (DIM / 4)) return;
        int node = t >> 5;               // 32 float4 per node
        int c4 = t & 31;
        float4 v = *(const float4*)(h + (size_t)node * DIM + c4 * 4);
        ushort4 p;
        p.x = f32_to_bf16(v.x); p.y = f32_to_bf16(v.y);
        p.z = f32_to_bf16(v.z); p.w = f32_to_bf16(v.w);
        int byteoff = (c4 * 8) ^ ((node & 7) << 4);
        *(ushort4*)((char*)(X + (size_t)node * 256) + byteoff) = p;
        return;
    }
    b -= PREP_CONV_BLKS;
    {
        int e = b * 256 + threadIdx.x;
        if (e < EDGES) atomicAdd(&cnt[ei[EDGES + e]], 1);
    }
}

// ---------------------------------------------------------------------------
// Scan (3 kernels)
// ---------------------------------------------------------------------------
__global__ __launch_bounds__(256) void mgl_scan_block_kernel(
    const int* __restrict__ cnt, int* __restrict__ row_start, int* __restrict__ bsum)
{
    __shared__ int sdata[256];
    int t = threadIdx.x;
    int base = blockIdx.x * SCAN_CHUNK + t * 4;
    int v[4];
    #pragma unroll
    for (int i = 0; i < 4; ++i) {
        int idx = base + i;
        v[i] = (idx < N_NODES) ? cnt[idx] : 0;
    }
    int tsum = v[0] + v[1] + v[2] + v[3];
    sdata[t] = tsum;
    __syncthreads();
    for (int off = 1; off < 256; off <<= 1) {
        int x = (t >= off) ? sdata[t - off] : 0;
        __syncthreads();
        sdata[t] += x;
        __syncthreads();
    }
    int run = (t > 0) ? sdata[t - 1] : 0;
    #pragma unroll
    for (int i = 0; i < 4; ++i) {
        int idx = base + i;
        if (idx < N_NODES) row_start[idx] = run;
        run += v[i];
    }
    if (t == 255) bsum[blockIdx.x] = sdata[255];
}

__global__ __launch_bounds__(128) void mgl_scan_bsum_kernel(int* __restrict__ bsum)
{
    __shared__ int sd[128];
    int t = threadIdx.x;
    int v = (t < SCAN_NBLK) ? bsum[t] : 0;
    sd[t] = v;
    __syncthreads();
    for (int off = 1; off < 128; off <<= 1) {
        int x = (t >= off) ? sd[t - off] : 0;
        __syncthreads();
        sd[t] += x;
        __syncthreads();
    }
    if (t < SCAN_NBLK) bsum[t] = sd[t] - v;  // exclusive
}

__global__ __launch_bounds__(256) void mgl_scan_add_kernel(
    int* __restrict__ row_start, const int* __restrict__ bsum)
{
    int i = blockIdx.x * 256 + threadIdx.x;
    if (i < N_NODES) row_start[i] += bsum[i / SCAN_CHUNK];
    if (i == 0) row_start[N_NODES] = EDGES;
}

// ---------------------------------------------------------------------------
// Fill: consume leftover counts with atomicSub (cnt ends at 0 -> deterministic
// across graph replays since prep re-counts after the single memset).
// ---------------------------------------------------------------------------
__global__ __launch_bounds__(256) void mgl_fill_kernel(
    const int* __restrict__ ei, const int* __restrict__ row_start,
    int* __restrict__ cnt, int* __restrict__ csr)
{
    int e = blockIdx.x * 256 + threadIdx.x;
    if (e >= EDGES) return;
    int s = ei[e];
    int t = ei[EDGES + e];
    int pos = atomicSub(&cnt[t], 1) - 1;
    csr[row_start[t] + pos] = s;
}

// ---------------------------------------------------------------------------
// Gather-mean (one wave/node): neighbor ids loaded 64-wide, shfl-broadcast.
// ---------------------------------------------------------------------------
__global__ __launch_bounds__(256) void mgl_gather_mean_kernel(
    const unsigned short* __restrict__ Xb, const int* __restrict__ row_start,
    const int* __restrict__ csr, unsigned short* __restrict__ X)
{
    int v = blockIdx.x * 4 + (threadIdx.x >> 6);
    if (v >= N_NODES) return;
    int lane = threadIdx.x & 63;
    int beg = row_start[v];
    int nb = row_start[v + 1] - beg;
    int laneByte = lane * 4;              // logical byte of elems {2lane, 2lane+1}
    const char* xb = (const char*)Xb;

    if (nb > 0) {
        float2 acc = make_float2(0.f, 0.f);
        for (int base = 0; base < nb; base += 64) {
            int rem = nb - base; if (rem > 64) rem = 64;
            int sv = (lane < rem) ? csr[beg + base + lane] : 0;
            for (int j = 0; j < rem; ++j) {
                int s = __shfl(sv, j);
                unsigned int pk = *(const unsigned int*)(
                    xb + (size_t)s * 512 + (laneByte ^ ((s & 7) << 4)));
                acc.x += __uint_as_float(pk << 16);
                acc.y += __uint_as_float(pk & 0xffff0000u);
            }
        }
        float inv = 1.f / (float)nb;
        unsigned int po = (unsigned int)f32_to_bf16(acc.x * inv) |
                          ((unsigned int)f32_to_bf16(acc.y * inv) << 16);
        *(unsigned int*)((char*)(X + (size_t)v * 256) +
                         ((256 + laneByte) ^ ((v & 7) << 4))) = po;
    } else {
        unsigned int pk = *(const unsigned int*)(
            xb + (size_t)v * 512 + (laneByte ^ ((v & 7) << 4)));
        *(unsigned int*)((char*)(X + (size_t)v * 256) +
                         ((256 + laneByte) ^ ((v & 7) << 4))) = pk;
    }
}

// ---------------------------------------------------------------------------
// Persistent weight-resident MFMA GEMM.
//   out[m][nc] = f( sum_k Xr[m][k] * Wt[nc][k] + bias[nc] )
// 8 waves (512 thr) as 4m x 2n; wave-tile 64m x (NI*16)n; m-tile 256 rows.
// W n-slice (NI*32 rows x KTOT) = 64 KB resident in LDS, staged ONCE.
// X streamed as [256m][64k] 32 KB chunks, double-buffered, depth-1 prefetch
// with counted vmcnt(4) (never 0 mid-loop). Grid = 256 blocks (1/CU),
// NGROUPS n-slices x PARTS m-partitions; chunked XCD map puts all n-groups
// of an m-range on one XCD.
// ---------------------------------------------------------------------------
template<int KTOT, int NI, int NGROUPS, int PARTS, bool GELU_OUT>
__global__ __launch_bounds__(512) void mgl_mlp_kernel(
    const unsigned short* __restrict__ Wt,   // [ntot][KTOT] bf16 swizzled
    const unsigned short* __restrict__ Xr,   // [MROWS_PAD][KTOT] bf16 swizzled
    const float* __restrict__ bias,
    void* __restrict__ outp)
{
    constexpr int NT = KTOT / 64;            // K-steps per m-tile (4 / 8)
    constexpr int KB = KTOT * 2;             // W row bytes (512 / 1024)
    constexpr int WROWS = NI * 32;           // 128 / 64
    constexpr int SHIFT = (NT == 4) ? 2 : 3;
    constexpr int TILES = MROWS_PAD / 256;   // 391

    __shared__ char lds[65536 + 2 * 32768];  // W 64 KB + X dbuf 2x32 KB
    char* ldsW = lds;
    char* ldsX = lds + 65536;

    int tid = threadIdx.x;
    int w = tid >> 6, l = tid & 63;

    // chunked XCD map: physical XCD = blockIdx%8; group 32 consecutive vbids
    // per XCD so all NGROUPS of an m-partition share one L2.
    int vbid = ((blockIdx.x & 7) << 5) + (blockIdx.x >> 3);
    int p = vbid / NGROUPS;                  // m-partition
    int ng = vbid % NGROUPS;                 // n-slice
    int T = (TILES - p + PARTS - 1) / PARTS; // tiles for this partition
    int C = T << SHIFT;                      // total K-step chunks

    int wm = w >> 1, wn = w & 1;
    int r16 = l & 15, kq = l >> 4;
    int rowmask = (r16 & 7) << 4;

    // ---- stage resident W slice (64 KB, once) ----
    {
        const char* wg = (const char*)Wt + (size_t)ng * WROWS * KB;
        #pragma unroll
        for (int i = 0; i < 8; ++i) {
            int byte = i * 8192 + tid * 16;
            int row = byte / KB, col = byte & (KB - 1);
            gload16(wg + (size_t)row * KB + col, ldsW + byte);
        }
    }
    // ---- prologue: X chunk 0 (tile p, kt 0) ----
    {
        int m0 = p * 256;
        #pragma unroll
        for (int i = 0; i < 4; ++i) {
            int byte = i * 8192 + tid * 16;
            int row = byte >> 7, col = byte & 127;
            gload16((const char*)Xr + (size_t)(m0 + row) * KB + col, ldsX + byte);
        }
    }

    f32x4 acc[4][NI] = {};

    for (int c = 0; c < C; ++c) {
        int kt = c & (NT - 1);
        char* bufc = ldsX + (c & 1) * 32768;
        if (c + 1 < C) {
            int c2 = c + 1;
            int kt2 = c2 & (NT - 1);
            int m02 = (p + (c2 >> SHIFT) * PARTS) * 256;
            char* bufn = ldsX + (c2 & 1) * 32768;
            #pragma unroll
            for (int i = 0; i < 4; ++i) {
                int byte = i * 8192 + tid * 16;
                int row = byte >> 7, col = byte & 127;
                gload16((const char*)Xr + (size_t)(m02 + row) * KB + kt2 * 128 + col,
                        bufn + byte);
            }
            asm volatile("s_waitcnt vmcnt(4)" ::: "memory");  // chunk c landed
        } else {
            asm volatile("s_waitcnt vmcnt(0)" ::: "memory");
        }
        __builtin_amdgcn_s_barrier();

        #pragma unroll
        for (int kk = 0; kk < 2; ++kk) {
            int posb = (kk * 64 + kq * 16) ^ rowmask;
            bf16x8 a[NI], b[4];
            #pragma unroll
            for (int ni = 0; ni < NI; ++ni)
                a[ni] = *(const bf16x8*)(ldsW +
                    (size_t)(wn * (NI * 16) + ni * 16 + r16) * KB + kt * 128 + posb);
            #pragma unroll
            for (int mi = 0; mi < 4; ++mi)
                b[mi] = *(const bf16x8*)(bufc + (wm * 64 + mi * 16 + r16) * 128 + posb);
            #pragma unroll
            for (int mi = 0; mi < 4; ++mi)
                #pragma unroll
                for (int ni = 0; ni < NI; ++ni)
                    acc[mi][ni] = __builtin_amdgcn_mfma_f32_16x16x32_bf16(
                        a[ni], b[mi], acc[mi][ni], 0, 0, 0);
        }
        __builtin_amdgcn_s_barrier();   // all reads of bufc done before re-stage

        if (kt == NT - 1) {
            // ---- epilogue for finished m-tile ----
            int m0 = (p + (c >> SHIFT) * PARTS) * 256;
            #pragma unroll
            for (int mi = 0; mi < 4; ++mi) {
                int m = m0 + wm * 64 + mi * 16 + r16;
                #pragma unroll
                for (int ni = 0; ni < NI; ++ni) {
                    int nc = ng * (NI * 32) + wn * (NI * 16) + ni * 16 + kq * 4;
                    float4 bv = *(const float4*)(bias + nc);
                    float x0 = acc[mi][ni][0] + bv.x;
                    float x1 = acc[mi][ni][1] + bv.y;
                    float x2 = acc[mi][ni][2] + bv.z;
                    float x3 = acc[mi][ni][3] + bv.w;
                    if (GELU_OUT) {
                        ushort4 pk;
                        pk.x = f32_to_bf16(gelu_f(x0));
                        pk.y = f32_to_bf16(gelu_f(x1));
                        pk.z = f32_to_bf16(gelu_f(x2));
                        pk.w = f32_to_bf16(gelu_f(x3));
                        unsigned short* row = (unsigned short*)outp + (size_t)m * HID;
                        int byteoff = (nc * 2) ^ ((m & 7) << 4);   // swizzled hdn
                        *(ushort4*)((char*)row + byteoff) = pk;
                    } else if (m < N_NODES) {
                        float4 o = make_float4(x0, x1, x2, x3);
                        *(float4*)((float*)outp + (size_t)m * DIM + nc) = o;
                    }
                    acc[mi][ni] = (f32x4){0.f, 0.f, 0.f, 0.f};
                }
            }
        }
    }
}

// ---------------------------------------------------------------------------
extern "C" void kernel_launch(void* const* d_in, const int* in_sizes, int n_in,
                              void* d_out, int out_size, void* d_ws, size_t ws_size,
                              hipStream_t stream) {
    const float* h  = (const float*)d_in[0];
    const int*   ei = (const int*)d_in[1];
    const float* W1 = (const float*)d_in[2];
    const float* b1 = (const float*)d_in[3];
    const float* W2 = (const float*)d_in[4];
    const float* b2 = (const float*)d_in[5];
    float* out = (float*)d_out;

    // workspace layout
    unsigned short* X   = (unsigned short*)d_ws;             // MROWS_PAD*256 bf16
    unsigned short* hdn = X + (size_t)MROWS_PAD * 256;       // MROWS_PAD*512 bf16
    unsigned short* W1T = hdn + (size_t)MROWS_PAD * 512;     // 512*256 bf16
    unsigned short* W2T = W1T + 512 * 256;                   // 128*512 bf16
    int* cnt = (int*)(W2T + 128 * 512);                      // N
    int* row_start = cnt + N_NODES;                          // N+1
    int* bsum = row_start + N_NODES + 1;                     // 128
    int* csr = bsum + 128;                                   // E

    hipMemsetAsync(cnt, 0, N_NODES * sizeof(int), stream);
    mgl_prep_kernel<<<PREP_TOTAL, 256, 0, stream>>>(h, ei, W1, W2, X, W1T, W2T, cnt);
    mgl_scan_block_kernel<<<SCAN_NBLK, 256, 0, stream>>>(cnt, row_start, bsum);
    mgl_scan_bsum_kernel<<<1, 128, 0, stream>>>(bsum);
    mgl_scan_add_kernel<<<(N_NODES + 255) / 256, 256, 0, stream>>>(row_start, bsum);
    mgl_fill_kernel<<<(EDGES + 255) / 256, 256, 0, stream>>>(ei, row_start, cnt, csr);
    mgl_gather_mean_kernel<<<(N_NODES + 3) / 4, 256, 0, stream>>>(X, row_start, csr, X);

    // MLP via persistent weight-resident MFMA GEMMs (grid 256 = 1 block/CU)
    mgl_mlp_kernel<256, 4, 4, 64, true><<<256, 512, 0, stream>>>(W1T, X, b1, hdn);
    mgl_mlp_kernel<512, 2, 2, 128, false><<<256, 512, 0, stream>>>(W2T, hdn, b2, out);
}

// Round 8
// 227.782 us; speedup vs baseline: 1.0240x; 1.0240x over previous
//
#include <hip/hip_runtime.h>
#include <hip/hip_bf16.h>
#include <math.h>

#define N_NODES 100000
#define DIM 128
#define HID 512
#define EDGES 600000
#define SCAN_CHUNK 1024
#define SCAN_NBLK ((N_NODES + SCAN_CHUNK - 1) / SCAN_CHUNK)  // 98
#define MROWS_PAD 100096   // 1564 * 64

typedef short bf16x8 __attribute__((ext_vector_type(8)));
typedef float f32x4 __attribute__((ext_vector_type(4)));

// Swizzle convention (rule #21 both-sides): for every bf16 staging buffer
// (X, W1T, W2T) physical byte within a row = logical byte XOR ((row&7)<<4).
// XOR touches bits 4..6 only -> permutes 16-B slots within each 128-B chunk,
// so any 128-B-aligned sub-chunk copied linearly (global_load_lds) keeps the
// same internal permutation, and swizzled ds_read / global reads land right.

__device__ inline unsigned short f32_to_bf16(float f) {
    unsigned int u = __float_as_uint(f);
    u += 0x7fff + ((u >> 16) & 1);
    return (unsigned short)(u >> 16);
}

// fast GELU: tanh form via hw exp2 + rcp. |gelu_tanh - gelu_erf| <= ~5e-4.
__device__ inline float gelu_f(float x) {
    float x3 = x * x * x;
    float y = 0.7978845608028654f * x + 0.0356774081f * x3;
    float e = exp2f(y * 2.8853900817779268f);                 // exp(2y)
    float t = 1.0f - 2.0f * __builtin_amdgcn_rcpf(e + 1.0f);  // tanh(y)
    return 0.5f * x * (1.0f + t);
}

__device__ inline void gload16(const void* g, void* l) {
    __builtin_amdgcn_global_load_lds(
        (const __attribute__((address_space(1))) unsigned int*)g,
        (__attribute__((address_space(3))) unsigned int*)l,
        16, 0, 0);
}

// ---------------------------------------------------------------------------
// Fused prep kernel: W1 transpose | W2 transpose | h->bf16 convert | dst count
// ---------------------------------------------------------------------------
#define PREP_W1_BLKS 512
#define PREP_W2_BLKS 128
#define PREP_CONV_BLKS 12500                  // N_NODES*32/256
#define PREP_COUNT_BLKS ((EDGES + 255) / 256) // 2344
#define PREP_TOTAL (PREP_W1_BLKS + PREP_W2_BLKS + PREP_CONV_BLKS + PREP_COUNT_BLKS)

__global__ __launch_bounds__(256) void mgl_prep_kernel(
    const float* __restrict__ h, const int* __restrict__ ei,
    const float* __restrict__ W1, const float* __restrict__ W2,
    unsigned short* __restrict__ X, unsigned short* __restrict__ W1T,
    unsigned short* __restrict__ W2T, int* __restrict__ cnt)
{
    int b = blockIdx.x;
    if (b < PREP_W1_BLKS) {
        int n = b;                       // 0..511
        int k = threadIdx.x;             // 0..255
        unsigned short val = f32_to_bf16(W1[(size_t)k * HID + n]);
        int byteoff = (k * 2) ^ ((n & 7) << 4);
        *(unsigned short*)((char*)(W1T + (size_t)n * 256) + byteoff) = val;
        return;
    }
    b -= PREP_W1_BLKS;
    if (b < PREP_W2_BLKS) {
        int n = b;                       // 0..127
        #pragma unroll
        for (int it = 0; it < 2; ++it) {
            int k = threadIdx.x + it * 256;  // 0..511
            unsigned short val = f32_to_bf16(W2[(size_t)k * DIM + n]);
            int byteoff = (k * 2) ^ ((n & 7) << 4);
            *(unsigned short*)((char*)(W2T + (size_t)n * 512) + byteoff) = val;
        }
        return;
    }
    b -= PREP_W2_BLKS;
    if (b < PREP_CONV_BLKS) {
        int t = b * 256 + threadIdx.x;
        if (t >= N_NODES * (DIM / 4)) return;
        int node = t >> 5;               // 32 float4 per node
        int c4 = t & 31;
        float4 v = *(const float4*)(h + (size_t)node * DIM + c4 * 4);
        ushort4 p;
        p.x = f32_to_bf16(v.x); p.y = f32_to_bf16(v.y);
        p.z = f32_to_bf16(v.z); p.w = f32_to_bf16(v.w);
        int byteoff = (c4 * 8) ^ ((node & 7) << 4);
        *(ushort4*)((char*)(X + (size_t)node * 256) + byteoff) = p;
        return;
    }
    b -= PREP_CONV_BLKS;
    {
        int e = b * 256 + threadIdx.x;
        if (e < EDGES) atomicAdd(&cnt[ei[EDGES + e]], 1);
    }
}

// ---------------------------------------------------------------------------
// Scan (3 kernels)
// ---------------------------------------------------------------------------
__global__ __launch_bounds__(256) void mgl_scan_block_kernel(
    const int* __restrict__ cnt, int* __restrict__ row_start, int* __restrict__ bsum)
{
    __shared__ int sdata[256];
    int t = threadIdx.x;
    int base = blockIdx.x * SCAN_CHUNK + t * 4;
    int v[4];
    #pragma unroll
    for (int i = 0; i < 4; ++i) {
        int idx = base + i;
        v[i] = (idx < N_NODES) ? cnt[idx] : 0;
    }
    int tsum = v[0] + v[1] + v[2] + v[3];
    sdata[t] = tsum;
    __syncthreads();
    for (int off = 1; off < 256; off <<= 1) {
        int x = (t >= off) ? sdata[t - off] : 0;
        __syncthreads();
        sdata[t] += x;
        __syncthreads();
    }
    int run = (t > 0) ? sdata[t - 1] : 0;
    #pragma unroll
    for (int i = 0; i < 4; ++i) {
        int idx = base + i;
        if (idx < N_NODES) row_start[idx] = run;
        run += v[i];
    }
    if (t == 255) bsum[blockIdx.x] = sdata[255];
}

__global__ __launch_bounds__(128) void mgl_scan_bsum_kernel(int* __restrict__ bsum)
{
    __shared__ int sd[128];
    int t = threadIdx.x;
    int v = (t < SCAN_NBLK) ? bsum[t] : 0;
    sd[t] = v;
    __syncthreads();
    for (int off = 1; off < 128; off <<= 1) {
        int x = (t >= off) ? sd[t - off] : 0;
        __syncthreads();
        sd[t] += x;
        __syncthreads();
    }
    if (t < SCAN_NBLK) bsum[t] = sd[t] - v;  // exclusive
}

__global__ __launch_bounds__(256) void mgl_scan_add_kernel(
    int* __restrict__ row_start, const int* __restrict__ bsum)
{
    int i = blockIdx.x * 256 + threadIdx.x;
    if (i < N_NODES) row_start[i] += bsum[i / SCAN_CHUNK];
    if (i == 0) row_start[N_NODES] = EDGES;
}

// ---------------------------------------------------------------------------
// Fill: consume leftover counts with atomicSub (cnt ends at 0 -> deterministic
// across graph replays since prep re-counts after the single memset).
// ---------------------------------------------------------------------------
__global__ __launch_bounds__(256) void mgl_fill_kernel(
    const int* __restrict__ ei, const int* __restrict__ row_start,
    int* __restrict__ cnt, int* __restrict__ csr)
{
    int e = blockIdx.x * 256 + threadIdx.x;
    if (e >= EDGES) return;
    int s = ei[e];
    int t = ei[EDGES + e];
    int pos = atomicSub(&cnt[t], 1) - 1;
    csr[row_start[t] + pos] = s;
}

// ---------------------------------------------------------------------------
// Gather-mean (one wave/node): neighbor ids loaded 64-wide, shfl-broadcast.
// ---------------------------------------------------------------------------
__global__ __launch_bounds__(256) void mgl_gather_mean_kernel(
    const unsigned short* __restrict__ Xb, const int* __restrict__ row_start,
    const int* __restrict__ csr, unsigned short* __restrict__ X)
{
    int v = blockIdx.x * 4 + (threadIdx.x >> 6);
    if (v >= N_NODES) return;
    int lane = threadIdx.x & 63;
    int beg = row_start[v];
    int nb = row_start[v + 1] - beg;
    int laneByte = lane * 4;              // logical byte of elems {2lane, 2lane+1}
    const char* xb = (const char*)Xb;

    if (nb > 0) {
        float2 acc = make_float2(0.f, 0.f);
        for (int base = 0; base < nb; base += 64) {
            int rem = nb - base; if (rem > 64) rem = 64;
            int sv = (lane < rem) ? csr[beg + base + lane] : 0;
            for (int j = 0; j < rem; ++j) {
                int s = __shfl(sv, j);
                unsigned int pk = *(const unsigned int*)(
                    xb + (size_t)s * 512 + (laneByte ^ ((s & 7) << 4)));
                acc.x += __uint_as_float(pk << 16);
                acc.y += __uint_as_float(pk & 0xffff0000u);
            }
        }
        float inv = 1.f / (float)nb;
        unsigned int po = (unsigned int)f32_to_bf16(acc.x * inv) |
                          ((unsigned int)f32_to_bf16(acc.y * inv) << 16);
        *(unsigned int*)((char*)(X + (size_t)v * 256) +
                         ((256 + laneByte) ^ ((v & 7) << 4))) = po;
    } else {
        unsigned int pk = *(const unsigned int*)(
            xb + (size_t)v * 512 + (laneByte ^ ((v & 7) << 4)));
        *(unsigned int*)((char*)(X + (size_t)v * 256) +
                         ((256 + laneByte) ^ ((v & 7) << 4))) = pk;
    }
}

// ---------------------------------------------------------------------------
// FUSED MLP: out = gelu([h,agg] @ W1 + b1) @ W2 + b2, one block per 64 rows.
//   - X rows (64 x 256 bf16) in REGISTERS (16 bf16x8/lane, loaded once)
//   - hdn tile (64 x 512 bf16 = 64 KB) in LDS, swizzled, never hits HBM
//   - W1/W2 tiles ([128n][64k] = 16 KB) stream through a 4-slot LDS ring
//     with CONTINUOUS counted vmcnt(4) across all 24 steps (stage sigma
//     issued at step sigma-3; <=3 stages = 6 loads in flight; vmcnt(4)
//     lands the oldest). W is L2-resident (384 KB shared by all blocks).
//   - per-step s_barrier bounds wave skew to 1 step -> ring reuse race-free
//     (slot (s+3)&3 last read at compute s-1, sealed by barrier s).
// 8 waves = 2m x 4n; wave-tile 32m x 32n per phase-1 n-group / phase-2.
// LDS total 128 KB (proven size) -> 1 block/CU.
// ---------------------------------------------------------------------------
__global__ __launch_bounds__(512) void mgl_fused_mlp_kernel(
    const unsigned short* __restrict__ W1T,  // [512][256] bf16 swizzled
    const unsigned short* __restrict__ W2T,  // [128][512] bf16 swizzled
    const unsigned short* __restrict__ Xr,   // [MROWS_PAD][256] bf16 swizzled
    const float* __restrict__ b1f, const float* __restrict__ b2f,
    float* __restrict__ outp)
{
    __shared__ char lds[131072];
    char* ring = lds;            // 4 x 16384
    char* hdnl = lds + 65536;    // 64 rows x 1024 B

    const int tid = threadIdx.x;
    const int w = tid >> 6, l = tid & 63;
    const int wm = w >> 2, wn = w & 3;       // 2m x 4n waves
    const int r16 = l & 15, kq = l >> 4;
    const int rowmask = (r16 & 7) << 4;
    const int m0 = blockIdx.x * 64;

    // ---- bias preload (drained by the vmcnt(0) below, before ring starts) --
    float4 b1v[4][2], b2v[2];
    #pragma unroll
    for (int ng = 0; ng < 4; ++ng)
        #pragma unroll
        for (int ni = 0; ni < 2; ++ni)
            b1v[ng][ni] = *(const float4*)(b1f + ng * 128 + wn * 32 + ni * 16 + kq * 4);
    #pragma unroll
    for (int ni = 0; ni < 2; ++ni)
        b2v[ni] = *(const float4*)(b2f + wn * 32 + ni * 16 + kq * 4);

    // ---- X fragments -> registers (64 VGPR), loaded once ----
    bf16x8 xf[2][4][2];
    #pragma unroll
    for (int mi = 0; mi < 2; ++mi) {
        int m = m0 + wm * 32 + mi * 16 + r16;
        const char* xrow = (const char*)Xr + (size_t)m * 512;
        int swz = (m & 7) << 4;
        #pragma unroll
        for (int kt = 0; kt < 4; ++kt)
            #pragma unroll
            for (int kk = 0; kk < 2; ++kk)
                xf[mi][kt][kk] = *(const bf16x8*)(
                    xrow + ((kt * 128 + kk * 64 + kq * 16) ^ swz));
    }
    asm volatile("s_waitcnt vmcnt(0)" ::: "memory");  // bias + X landed

    // ---- W stage helpers: 16 KB tile = 16 wave-chunks of 1024 B ----
    // gload16 dst must be wave-uniform base + lane*16 (m104): chunk c = w+i*8,
    // lane covers row c*8 + (l>>3), col (l&7)*16 of the [128n][64k] tile.
    auto stageW1 = [&](int slot, int ng, int kt) {
        #pragma unroll
        for (int i = 0; i < 2; ++i) {
            int c = w + i * 8;
            int row = c * 8 + (l >> 3);
            int col = (l & 7) * 16;
            const char* g = (const char*)W1T +
                (size_t)(ng * 128 + row) * 512 + kt * 128 + col;
            gload16(g, ring + slot * 16384 + c * 1024 + l * 16);
        }
    };
    auto stageW2 = [&](int slot, int kt) {
        #pragma unroll
        for (int i = 0; i < 2; ++i) {
            int c = w + i * 8;
            int row = c * 8 + (l >> 3);
            int col = (l & 7) * 16;
            const char* g = (const char*)W2T +
                (size_t)row * 1024 + kt * 128 + col;
            gload16(g, ring + slot * 16384 + c * 1024 + l * 16);
        }
    };

    // prologue: stages sigma = 0,1,2
    stageW1(0, 0, 0);
    stageW1(1, 0, 1);
    stageW1(2, 0, 2);

    f32x4 acc[2][2] = {};

    // ================= phase 1: hdn = gelu(X @ W1 + b1) =================
    #pragma unroll
    for (int s = 0; s < 16; ++s) {
        asm volatile("s_waitcnt vmcnt(4)" ::: "memory");  // stage s landed
        __builtin_amdgcn_s_barrier();

        const int ng = s >> 2, kt = s & 3;
        const char* wbase = ring + (s & 3) * 16384;
        #pragma unroll
        for (int kk = 0; kk < 2; ++kk) {
            bf16x8 a[2];
            #pragma unroll
            for (int ni = 0; ni < 2; ++ni)
                a[ni] = *(const bf16x8*)(wbase +
                    (wn * 32 + ni * 16 + r16) * 128 + ((kk * 64 + kq * 16) ^ rowmask));
            #pragma unroll
            for (int mi = 0; mi < 2; ++mi)
                #pragma unroll
                for (int ni = 0; ni < 2; ++ni)
                    acc[mi][ni] = __builtin_amdgcn_mfma_f32_16x16x32_bf16(
                        a[ni], xf[mi][kt][kk], acc[mi][ni], 0, 0, 0);
        }

        // issue stage sigma = s+3 (continues into W2 tiles seamlessly)
        {
            const int sg = s + 3;
            if (sg < 16) stageW1(sg & 3, sg >> 2, sg & 3);
            else         stageW2(sg & 3, sg - 16);
        }

        if (kt == 3) {  // n-group epilogue: bias + gelu -> hdn LDS (bf16)
            #pragma unroll
            for (int mi = 0; mi < 2; ++mi) {
                int ml = wm * 32 + mi * 16 + r16;
                int mswz = (ml & 7) << 4;
                #pragma unroll
                for (int ni = 0; ni < 2; ++ni) {
                    int ncl = ng * 128 + wn * 32 + ni * 16 + kq * 4;
                    float4 bv = b1v[ng][ni];
                    ushort4 pk;
                    pk.x = f32_to_bf16(gelu_f(acc[mi][ni][0] + bv.x));
                    pk.y = f32_to_bf16(gelu_f(acc[mi][ni][1] + bv.y));
                    pk.z = f32_to_bf16(gelu_f(acc[mi][ni][2] + bv.z));
                    pk.w = f32_to_bf16(gelu_f(acc[mi][ni][3] + bv.w));
                    *(ushort4*)(hdnl + ml * 1024 + ((ncl * 2) ^ mswz)) = pk;
                    acc[mi][ni] = (f32x4){0.f, 0.f, 0.f, 0.f};
                }
            }
        }
    }

    // ---- transition: all hdn ds_writes visible to all waves ----
    asm volatile("s_waitcnt lgkmcnt(0)" ::: "memory");
    __builtin_amdgcn_s_barrier();

    // ================= phase 2: out = hdn @ W2 + b2 =================
    f32x4 acc2[2][2] = {};
    #pragma unroll
    for (int s2 = 0; s2 < 8; ++s2) {
        if (s2 < 6)      asm volatile("s_waitcnt vmcnt(4)" ::: "memory");
        else if (s2 == 6) asm volatile("s_waitcnt vmcnt(2)" ::: "memory");
        else              asm volatile("s_waitcnt vmcnt(0)" ::: "memory");
        __builtin_amdgcn_s_barrier();

        const char* wbase = ring + (s2 & 3) * 16384;
        #pragma unroll
        for (int kk = 0; kk < 2; ++kk) {
            bf16x8 a[2], b[2];
            #pragma unroll
            for (int ni = 0; ni < 2; ++ni)
                a[ni] = *(const bf16x8*)(wbase +
                    (wn * 32 + ni * 16 + r16) * 128 + ((kk * 64 + kq * 16) ^ rowmask));
            #pragma unroll
            for (int mi = 0; mi < 2; ++mi) {
                int ml = wm * 32 + mi * 16 + r16;
                b[mi] = *(const bf16x8*)(hdnl + ml * 1024 +
                    ((s2 * 128 + kk * 64 + kq * 16) ^ ((ml & 7) << 4)));
            }
            #pragma unroll
            for (int mi = 0; mi < 2; ++mi)
                #pragma unroll
                for (int ni = 0; ni < 2; ++ni)
                    acc2[mi][ni] = __builtin_amdgcn_mfma_f32_16x16x32_bf16(
                        a[ni], b[mi], acc2[mi][ni], 0, 0, 0);
        }
        if (s2 + 3 < 8) stageW2((s2 + 3) & 3, s2 + 3);
    }

    // ---- final epilogue: out (f32) ----
    #pragma unroll
    for (int mi = 0; mi < 2; ++mi) {
        int m = m0 + wm * 32 + mi * 16 + r16;
        if (m >= N_NODES) continue;
        #pragma unroll
        for (int ni = 0; ni < 2; ++ni) {
            int nc = wn * 32 + ni * 16 + kq * 4;
            float4 o;
            o.x = acc2[mi][ni][0] + b2v[ni].x;
            o.y = acc2[mi][ni][1] + b2v[ni].y;
            o.z = acc2[mi][ni][2] + b2v[ni].z;
            o.w = acc2[mi][ni][3] + b2v[ni].w;
            *(float4*)(outp + (size_t)m * DIM + nc) = o;
        }
    }
}

// ---------------------------------------------------------------------------
extern "C" void kernel_launch(void* const* d_in, const int* in_sizes, int n_in,
                              void* d_out, int out_size, void* d_ws, size_t ws_size,
                              hipStream_t stream) {
    const float* h  = (const float*)d_in[0];
    const int*   ei = (const int*)d_in[1];
    const float* W1 = (const float*)d_in[2];
    const float* b1 = (const float*)d_in[3];
    const float* W2 = (const float*)d_in[4];
    const float* b2 = (const float*)d_in[5];
    float* out = (float*)d_out;

    // workspace layout (hdn eliminated)
    unsigned short* X   = (unsigned short*)d_ws;             // MROWS_PAD*256 bf16
    unsigned short* W1T = X + (size_t)MROWS_PAD * 256;       // 512*256 bf16
    unsigned short* W2T = W1T + 512 * 256;                   // 128*512 bf16
    int* cnt = (int*)(W2T + 128 * 512);                      // N
    int* row_start = cnt + N_NODES;                          // N+1
    int* bsum = row_start + N_NODES + 1;                     // 128
    int* csr = bsum + 128;                                   // E

    hipMemsetAsync(cnt, 0, N_NODES * sizeof(int), stream);
    mgl_prep_kernel<<<PREP_TOTAL, 256, 0, stream>>>(h, ei, W1, W2, X, W1T, W2T, cnt);
    mgl_scan_block_kernel<<<SCAN_NBLK, 256, 0, stream>>>(cnt, row_start, bsum);
    mgl_scan_bsum_kernel<<<1, 128, 0, stream>>>(bsum);
    mgl_scan_add_kernel<<<(N_NODES + 255) / 256, 256, 0, stream>>>(row_start, bsum);
    mgl_fill_kernel<<<(EDGES + 255) / 256, 256, 0, stream>>>(ei, row_start, cnt, csr);
    mgl_gather_mean_kernel<<<(N_NODES + 3) / 4, 256, 0, stream>>>(X, row_start, csr, X);

    // fused MLP: one block per 64 rows
    mgl_fused_mlp_kernel<<<MROWS_PAD / 64, 512, 0, stream>>>(W1T, W2T, X, b1, b2, out);
}

// Round 9
// 224.423 us; speedup vs baseline: 1.0394x; 1.0150x over previous
//
#include <hip/hip_runtime.h>
#include <hip/hip_bf16.h>
#include <math.h>

#define N_NODES 100000
#define DIM 128
#define HID 512
#define EDGES 600000
#define SCAN_CHUNK 1024
#define SCAN_NBLK ((N_NODES + SCAN_CHUNK - 1) / SCAN_CHUNK)  // 98
#define MROWS_PAD 100096
#define NCH1 (MROWS_PAD / 64)   // 1564 chunks for GEMM1
#define NCH2 (MROWS_PAD / 32)   // 3128 chunks for GEMM2

typedef short bf16x8 __attribute__((ext_vector_type(8)));
typedef float f32x4 __attribute__((ext_vector_type(4)));

// Swizzle convention (rule #21 both-sides): for every bf16 staging buffer
// (X, W1T, W2T, hdn) physical byte within a row = logical byte XOR
// ((row&7)<<4). XOR touches bits 4..6 only -> permutes 16-B slots within
// each 128-B chunk; linear copies (global_load_lds) preserve it; swizzled
// reads (global or ds) land right and are LDS-bank-conflict-free.

__device__ inline unsigned short f32_to_bf16(float f) {
    unsigned int u = __float_as_uint(f);
    u += 0x7fff + ((u >> 16) & 1);
    return (unsigned short)(u >> 16);
}

// fast GELU: tanh form via hw exp2 + rcp. |gelu_tanh - gelu_erf| <= ~5e-4.
__device__ inline float gelu_f(float x) {
    float x3 = x * x * x;
    float y = 0.7978845608028654f * x + 0.0356774081f * x3;
    float e = exp2f(y * 2.8853900817779268f);                 // exp(2y)
    float t = 1.0f - 2.0f * __builtin_amdgcn_rcpf(e + 1.0f);  // tanh(y)
    return 0.5f * x * (1.0f + t);
}

__device__ inline void gload16(const void* g, void* l) {
    __builtin_amdgcn_global_load_lds(
        (const __attribute__((address_space(1))) unsigned int*)g,
        (__attribute__((address_space(3))) unsigned int*)l,
        16, 0, 0);
}

// ---------------------------------------------------------------------------
// Fused prep kernel: W1 transpose | W2 transpose | h->bf16 convert | dst count
// ---------------------------------------------------------------------------
#define PREP_W1_BLKS 512
#define PREP_W2_BLKS 128
#define PREP_CONV_BLKS 12500                  // N_NODES*32/256
#define PREP_COUNT_BLKS ((EDGES + 255) / 256) // 2344
#define PREP_TOTAL (PREP_W1_BLKS + PREP_W2_BLKS + PREP_CONV_BLKS + PREP_COUNT_BLKS)

__global__ __launch_bounds__(256) void mgl_prep_kernel(
    const float* __restrict__ h, const int* __restrict__ ei,
    const float* __restrict__ W1, const float* __restrict__ W2,
    unsigned short* __restrict__ X, unsigned short* __restrict__ W1T,
    unsigned short* __restrict__ W2T, int* __restrict__ cnt)
{
    int b = blockIdx.x;
    if (b < PREP_W1_BLKS) {
        int n = b;                       // 0..511
        int k = threadIdx.x;             // 0..255
        unsigned short val = f32_to_bf16(W1[(size_t)k * HID + n]);
        int byteoff = (k * 2) ^ ((n & 7) << 4);
        *(unsigned short*)((char*)(W1T + (size_t)n * 256) + byteoff) = val;
        return;
    }
    b -= PREP_W1_BLKS;
    if (b < PREP_W2_BLKS) {
        int n = b;                       // 0..127
        #pragma unroll
        for (int it = 0; it < 2; ++it) {
            int k = threadIdx.x + it * 256;  // 0..511
            unsigned short val = f32_to_bf16(W2[(size_t)k * DIM + n]);
            int byteoff = (k * 2) ^ ((n & 7) << 4);
            *(unsigned short*)((char*)(W2T + (size_t)n * 512) + byteoff) = val;
        }
        return;
    }
    b -= PREP_W2_BLKS;
    if (b < PREP_CONV_BLKS) {
        int t = b * 256 + threadIdx.x;
        if (t >= N_NODES * (DIM / 4)) return;
        int node = t >> 5;               // 32 float4 per node
        int c4 = t & 31;
        float4 v = *(const float4*)(h + (size_t)node * DIM + c4 * 4);
        ushort4 p;
        p.x = f32_to_bf16(v.x); p.y = f32_to_bf16(v.y);
        p.z = f32_to_bf16(v.z); p.w = f32_to_bf16(v.w);
        int byteoff = (c4 * 8) ^ ((node & 7) << 4);
        *(ushort4*)((char*)(X + (size_t)node * 256) + byteoff) = p;
        return;
    }
    b -= PREP_CONV_BLKS;
    {
        int e = b * 256 + threadIdx.x;
        if (e < EDGES) atomicAdd(&cnt[ei[EDGES + e]], 1);
    }
}

// ---------------------------------------------------------------------------
// Scan (3 kernels)
// ---------------------------------------------------------------------------
__global__ __launch_bounds__(256) void mgl_scan_block_kernel(
    const int* __restrict__ cnt, int* __restrict__ row_start, int* __restrict__ bsum)
{
    __shared__ int sdata[256];
    int t = threadIdx.x;
    int base = blockIdx.x * SCAN_CHUNK + t * 4;
    int v[4];
    #pragma unroll
    for (int i = 0; i < 4; ++i) {
        int idx = base + i;
        v[i] = (idx < N_NODES) ? cnt[idx] : 0;
    }
    int tsum = v[0] + v[1] + v[2] + v[3];
    sdata[t] = tsum;
    __syncthreads();
    for (int off = 1; off < 256; off <<= 1) {
        int x = (t >= off) ? sdata[t - off] : 0;
        __syncthreads();
        sdata[t] += x;
        __syncthreads();
    }
    int run = (t > 0) ? sdata[t - 1] : 0;
    #pragma unroll
    for (int i = 0; i < 4; ++i) {
        int idx = base + i;
        if (idx < N_NODES) row_start[idx] = run;
        run += v[i];
    }
    if (t == 255) bsum[blockIdx.x] = sdata[255];
}

__global__ __launch_bounds__(128) void mgl_scan_bsum_kernel(int* __restrict__ bsum)
{
    __shared__ int sd[128];
    int t = threadIdx.x;
    int v = (t < SCAN_NBLK) ? bsum[t] : 0;
    sd[t] = v;
    __syncthreads();
    for (int off = 1; off < 128; off <<= 1) {
        int x = (t >= off) ? sd[t - off] : 0;
        __syncthreads();
        sd[t] += x;
        __syncthreads();
    }
    if (t < SCAN_NBLK) bsum[t] = sd[t] - v;  // exclusive
}

__global__ __launch_bounds__(256) void mgl_scan_add_kernel(
    int* __restrict__ row_start, const int* __restrict__ bsum)
{
    int i = blockIdx.x * 256 + threadIdx.x;
    if (i < N_NODES) row_start[i] += bsum[i / SCAN_CHUNK];
    if (i == 0) row_start[N_NODES] = EDGES;
}

// ---------------------------------------------------------------------------
// Fill: consume leftover counts with atomicSub (cnt ends 0 -> deterministic).
// ---------------------------------------------------------------------------
__global__ __launch_bounds__(256) void mgl_fill_kernel(
    const int* __restrict__ ei, const int* __restrict__ row_start,
    int* __restrict__ cnt, int* __restrict__ csr)
{
    int e = blockIdx.x * 256 + threadIdx.x;
    if (e >= EDGES) return;
    int s = ei[e];
    int t = ei[EDGES + e];
    int pos = atomicSub(&cnt[t], 1) - 1;
    csr[row_start[t] + pos] = s;
}

// ---------------------------------------------------------------------------
// Gather-mean (one wave/node): neighbor ids loaded 64-wide, shfl-broadcast.
// ---------------------------------------------------------------------------
__global__ __launch_bounds__(256) void mgl_gather_mean_kernel(
    const unsigned short* __restrict__ Xb, const int* __restrict__ row_start,
    const int* __restrict__ csr, unsigned short* __restrict__ X)
{
    int v = blockIdx.x * 4 + (threadIdx.x >> 6);
    if (v >= N_NODES) return;
    int lane = threadIdx.x & 63;
    int beg = row_start[v];
    int nb = row_start[v + 1] - beg;
    int laneByte = lane * 4;
    const char* xb = (const char*)Xb;

    if (nb > 0) {
        float2 acc = make_float2(0.f, 0.f);
        for (int base = 0; base < nb; base += 64) {
            int rem = nb - base; if (rem > 64) rem = 64;
            int sv = (lane < rem) ? csr[beg + base + lane] : 0;
            for (int j = 0; j < rem; ++j) {
                int s = __shfl(sv, j);
                unsigned int pk = *(const unsigned int*)(
                    xb + (size_t)s * 512 + (laneByte ^ ((s & 7) << 4)));
                acc.x += __uint_as_float(pk << 16);
                acc.y += __uint_as_float(pk & 0xffff0000u);
            }
        }
        float inv = 1.f / (float)nb;
        unsigned int po = (unsigned int)f32_to_bf16(acc.x * inv) |
                          ((unsigned int)f32_to_bf16(acc.y * inv) << 16);
        *(unsigned int*)((char*)(X + (size_t)v * 256) +
                         ((256 + laneByte) ^ ((v & 7) << 4))) = po;
    } else {
        unsigned int pk = *(const unsigned int*)(
            xb + (size_t)v * 512 + (laneByte ^ ((v & 7) << 4)));
        *(unsigned int*)((char*)(X + (size_t)v * 256) +
                         ((256 + laneByte) ^ ((v & 7) << 4))) = pk;
    }
}

// ---------------------------------------------------------------------------
// GEMM1 (hdn = gelu(X @ W1 + b1)): W1 RESIDENT IN REGISTERS per wave.
// 8 waves x 64 n-cols each = full N=512. W1 frags a1[4][8] = 128 VGPR,
// loaded once. X streamed in contiguous 64-row full-K chunks (32 KB) via a
// 3-slot LDS ring, depth-2 prefetch, ONE barrier + vmcnt per chunk, 128
// MFMA/wave between barriers. Grid 256 blocks, chunk stride 256.
// ---------------------------------------------------------------------------
__global__ __launch_bounds__(512, 2) void mgl_mlp1_kernel(
    const unsigned short* __restrict__ W1T,  // [512][256] bf16 swizzled
    const unsigned short* __restrict__ Xr,   // [MROWS_PAD][256] bf16 swizzled
    const float* __restrict__ b1f,
    unsigned short* __restrict__ hdn)        // [MROWS_PAD][512] bf16 swizzled
{
    __shared__ char ldsX[3 * 32768];
    const int tid = threadIdx.x;
    const int w = tid >> 6, l = tid & 63;
    const int r16 = l & 15, kq = l >> 4;
    const int rmask = (r16 & 7) << 4;
    const int n0w = w * 64;

    // resident W1 fragments + bias (retired by in-order vmcnt before use)
    bf16x8 a1[4][8];
    #pragma unroll
    for (int nb = 0; nb < 4; ++nb) {
        const char* wrow = (const char*)W1T + (size_t)(n0w + nb * 16 + r16) * 512;
        #pragma unroll
        for (int ks = 0; ks < 8; ++ks)
            a1[nb][ks] = *(const bf16x8*)(wrow + ((ks * 64 + kq * 16) ^ rmask));
    }
    float4 b1v[4];
    #pragma unroll
    for (int nb = 0; nb < 4; ++nb)
        b1v[nb] = *(const float4*)(b1f + n0w + nb * 16 + kq * 4);

    const int bid = blockIdx.x;
    const int nch = (NCH1 - bid + 255) >> 8;   // chunks: bid, bid+256, ...

    auto stage = [&](int slot, int cj) {       // 64 rows x 512 B contiguous
        const char* src = (const char*)Xr + (size_t)cj * 32768;
        char* dst = ldsX + slot * 32768;
        #pragma unroll
        for (int i = 0; i < 4; ++i) {
            int off = i * 8192 + tid * 16;
            gload16(src + off, dst + off);
        }
    };

    stage(0, bid);
    if (nch > 1) stage(1, bid + 256);

    for (int j = 0; j < nch; ++j) {
        // vmcnt(4): in-order retirement -> everything older than the newest
        // 4 loads (chunk j+1) has landed, incl. chunk j and W/bias loads.
        asm volatile("s_waitcnt vmcnt(4)" ::: "memory");
        __builtin_amdgcn_s_barrier();          // all waves staged chunk j
        asm volatile("" ::: "memory");
        if (j + 2 < nch) stage((j + 2) % 3, bid + (j + 2) * 256);

        const char* bX = ldsX + (j % 3) * 32768;
        f32x4 acc[4][4] = {};
        #pragma unroll
        for (int ks = 0; ks < 8; ++ks) {
            bf16x8 b[4];
            #pragma unroll
            for (int mb = 0; mb < 4; ++mb)
                b[mb] = *(const bf16x8*)(bX + (mb * 16 + r16) * 512 +
                                         ((ks * 64 + kq * 16) ^ rmask));
            #pragma unroll
            for (int mb = 0; mb < 4; ++mb)
                #pragma unroll
                for (int nb = 0; nb < 4; ++nb)
                    acc[mb][nb] = __builtin_amdgcn_mfma_f32_16x16x32_bf16(
                        a1[nb][ks], b[mb], acc[mb][nb], 0, 0, 0);
        }

        // epilogue: bias + gelu -> hdn (bf16, swizzled); pad rows written too
        const size_t m0c = (size_t)(bid + j * 256) * 64;
        #pragma unroll
        for (int mb = 0; mb < 4; ++mb) {
            size_t m = m0c + mb * 16 + r16;
            char* hrow = (char*)hdn + m * 1024;
            #pragma unroll
            for (int nb = 0; nb < 4; ++nb) {
                int nc = n0w + nb * 16 + kq * 4;
                ushort4 pk;
                pk.x = f32_to_bf16(gelu_f(acc[mb][nb][0] + b1v[nb].x));
                pk.y = f32_to_bf16(gelu_f(acc[mb][nb][1] + b1v[nb].y));
                pk.z = f32_to_bf16(gelu_f(acc[mb][nb][2] + b1v[nb].z));
                pk.w = f32_to_bf16(gelu_f(acc[mb][nb][3] + b1v[nb].w));
                *(ushort4*)(hrow + ((nc * 2) ^ rmask)) = pk;
            }
        }
    }
}

// ---------------------------------------------------------------------------
// GEMM2 (out = hdn @ W2 + b2): W2 RESIDENT IN REGISTERS per wave.
// 8 waves x 16 n-cols = N=128. W2 frags a2[16] = 64 VGPR. hdn streamed in
// 32-row full-K chunks (32 KB) via 3-slot ring, same schedule as GEMM1.
// ---------------------------------------------------------------------------
__global__ __launch_bounds__(512, 2) void mgl_mlp2_kernel(
    const unsigned short* __restrict__ W2T,  // [128][512] bf16 swizzled
    const unsigned short* __restrict__ hdn,  // [MROWS_PAD][512] bf16 swizzled
    const float* __restrict__ b2f,
    float* __restrict__ outp)
{
    __shared__ char ldsH[3 * 32768];
    const int tid = threadIdx.x;
    const int w = tid >> 6, l = tid & 63;
    const int r16 = l & 15, kq = l >> 4;
    const int rmask = (r16 & 7) << 4;

    bf16x8 a2[16];
    {
        const char* wrow = (const char*)W2T + (size_t)(w * 16 + r16) * 1024;
        #pragma unroll
        for (int ks = 0; ks < 16; ++ks)
            a2[ks] = *(const bf16x8*)(wrow + ((ks * 64 + kq * 16) ^ rmask));
    }
    float4 b2v = *(const float4*)(b2f + w * 16 + kq * 4);

    const int bid = blockIdx.x;
    const int nch = (NCH2 - bid + 255) >> 8;   // chunks: bid, bid+256, ...

    auto stage = [&](int slot, int cj) {       // 32 rows x 1024 B contiguous
        const char* src = (const char*)hdn + (size_t)cj * 32768;
        char* dst = ldsH + slot * 32768;
        #pragma unroll
        for (int i = 0; i < 4; ++i) {
            int off = i * 8192 + tid * 16;
            gload16(src + off, dst + off);
        }
    };

    stage(0, bid);
    if (nch > 1) stage(1, bid + 256);

    for (int j = 0; j < nch; ++j) {
        asm volatile("s_waitcnt vmcnt(4)" ::: "memory");
        __builtin_amdgcn_s_barrier();
        asm volatile("" ::: "memory");
        if (j + 2 < nch) stage((j + 2) % 3, bid + (j + 2) * 256);

        const char* bH = ldsH + (j % 3) * 32768;
        f32x4 acc[2] = {};
        #pragma unroll
        for (int ks = 0; ks < 16; ++ks) {
            bf16x8 b[2];
            #pragma unroll
            for (int mb = 0; mb < 2; ++mb)
                b[mb] = *(const bf16x8*)(bH + (mb * 16 + r16) * 1024 +
                                         ((ks * 64 + kq * 16) ^ rmask));
            #pragma unroll
            for (int mb = 0; mb < 2; ++mb)
                acc[mb] = __builtin_amdgcn_mfma_f32_16x16x32_bf16(
                    a2[ks], b[mb], acc[mb], 0, 0, 0);
        }

        const size_t m0c = (size_t)(bid + j * 256) * 32;
        #pragma unroll
        for (int mb = 0; mb < 2; ++mb) {
            size_t m = m0c + mb * 16 + r16;
            if (m < N_NODES) {
                float4 o;
                o.x = acc[mb][0] + b2v.x;
                o.y = acc[mb][1] + b2v.y;
                o.z = acc[mb][2] + b2v.z;
                o.w = acc[mb][3] + b2v.w;
                *(float4*)(outp + m * DIM + w * 16 + kq * 4) = o;
            }
        }
    }
}

// ---------------------------------------------------------------------------
extern "C" void kernel_launch(void* const* d_in, const int* in_sizes, int n_in,
                              void* d_out, int out_size, void* d_ws, size_t ws_size,
                              hipStream_t stream) {
    const float* h  = (const float*)d_in[0];
    const int*   ei = (const int*)d_in[1];
    const float* W1 = (const float*)d_in[2];
    const float* b1 = (const float*)d_in[3];
    const float* W2 = (const float*)d_in[4];
    const float* b2 = (const float*)d_in[5];
    float* out = (float*)d_out;

    // workspace layout
    unsigned short* X   = (unsigned short*)d_ws;             // MROWS_PAD*256 bf16
    unsigned short* hdn = X + (size_t)MROWS_PAD * 256;       // MROWS_PAD*512 bf16
    unsigned short* W1T = hdn + (size_t)MROWS_PAD * 512;     // 512*256 bf16
    unsigned short* W2T = W1T + 512 * 256;                   // 128*512 bf16
    int* cnt = (int*)(W2T + 128 * 512);                      // N
    int* row_start = cnt + N_NODES;                          // N+1
    int* bsum = row_start + N_NODES + 1;                     // 128
    int* csr = bsum + 128;                                   // E

    hipMemsetAsync(cnt, 0, N_NODES * sizeof(int), stream);
    mgl_prep_kernel<<<PREP_TOTAL, 256, 0, stream>>>(h, ei, W1, W2, X, W1T, W2T, cnt);
    mgl_scan_block_kernel<<<SCAN_NBLK, 256, 0, stream>>>(cnt, row_start, bsum);
    mgl_scan_bsum_kernel<<<1, 128, 0, stream>>>(bsum);
    mgl_scan_add_kernel<<<(N_NODES + 255) / 256, 256, 0, stream>>>(row_start, bsum);
    mgl_fill_kernel<<<(EDGES + 255) / 256, 256, 0, stream>>>(ei, row_start, cnt, csr);
    mgl_gather_mean_kernel<<<(N_NODES + 3) / 4, 256, 0, stream>>>(X, row_start, csr, X);

    // MLP: W-in-register streaming GEMMs, 256 blocks each
    mgl_mlp1_kernel<<<256, 512, 0, stream>>>(W1T, X, b1, hdn);
    mgl_mlp2_kernel<<<256, 512, 0, stream>>>(W2T, hdn, b2, out);
}